// Round 10
// baseline (119.111 us; speedup 1.0000x reference)
//
#include <hip/hip_runtime.h>

// Sizes (fixed by the reference)
#define Bq 32
#define Gq 16
#define Oq 256
#define Nq 88
#define Tq 256

typedef short bf16x8 __attribute__((ext_vector_type(8)));   // 8 bf16 in 4 VGPRs
typedef float f32x4 __attribute__((ext_vector_type(4)));

static __device__ __forceinline__ short f2bf(float f) {
    return __builtin_bit_cast(short, (__bf16)f);  // RNE convert, bits as short
}

// out[b,n,o] = sum_{g,t} x[b,n,t] * y[b,g] * w[g,o,n,t] * mask[o,t] + bias[o]
//
// R10 = R9 (68.7us) + ONE change: occupancy 3 -> 4 blocks/CU
// (__launch_bounds__(256,4); LDS 34KB x 4 = 136KB <= 160KB). Post-NT the
// request stream is DRAM-direct; outstanding-bytes/CU was ~96KB (~1.6x the
// BW*latency product) -- raising MLP 33% tests whether request concurrency
// is the remaining 13% gap to the 6.29 TB/s ceiling.
//  - Weight staging: plain NT global_load_dwordx4 -> VGPR -> ds_write_b128
//    (regA=even g, regB=odd g), 8-12 loads in flight, counted vmcnt(4),
//    raw s_barrier; never drain to 0 until the tail.
//  - XOR swizzle on the ds_write address; reader unchanged (rule 21).
//  - y[b,g] applied per-g to the f32 MFMA partial.
__global__ __launch_bounds__(256, 4)
void mlm_mfma10(const float* __restrict__ x, const float* __restrict__ y,
                const float* __restrict__ w, const float* __restrict__ mask,
                const float* __restrict__ bias, float* __restrict__ out) {
    __shared__ float wbuf[2][4096];   // 2 x 16KB: [16 rows(o)][64 chunks x 4 floats]
    __shared__ float y_lds[512];      // y[b][g] row-major

    const int bid = blockIdx.x;
    const int n  = bid >> 4;          // 0..87
    const int o0 = (bid & 15) << 4;   // o-tile base

    const int tid  = threadIdx.x;
    const int wv   = tid >> 6;        // 0..3 -> t-range [wv*64, wv*64+64)
    const int lane = tid & 63;
    const int lo = lane & 15;         // A row-slot / B col (o) / C col
    const int hi = lane >> 4;         // k-group 0..3
    const int sr = lo & 7;            // read-side swizzle key (o-row = lo)

    y_lds[tid]       = y[tid];
    y_lds[tid + 256] = y[tid + 256];

    // A fragments (x -> bf16) and mask chunks: built once, live for all 16 g.
    // sigma: frag elem (hi,j): j<4 -> t = tA+j ; j>=4 -> t = tA+16+(j-4)
    bf16x8 afrag[2][2];               // [window W][b-half]
    f32x4 mka[2], mkb[2];
    const int tbase = wv * 64;
#pragma unroll
    for (int W = 0; W < 2; ++W) {
        const int ta = tbase + W * 32 + hi * 4;
        const int tb = ta + 16;
        f32x4 xa0 = *(const f32x4*)(x + ((size_t)lo * Nq + n) * Tq + ta);
        f32x4 xb0 = *(const f32x4*)(x + ((size_t)lo * Nq + n) * Tq + tb);
        f32x4 xa1 = *(const f32x4*)(x + ((size_t)(lo + 16) * Nq + n) * Tq + ta);
        f32x4 xb1 = *(const f32x4*)(x + ((size_t)(lo + 16) * Nq + n) * Tq + tb);
        mka[W] = *(const f32x4*)(mask + (size_t)(o0 + lo) * Tq + ta);
        mkb[W] = *(const f32x4*)(mask + (size_t)(o0 + lo) * Tq + tb);
#pragma unroll
        for (int j = 0; j < 4; ++j) {
            afrag[W][0][j]     = f2bf(xa0[j]);
            afrag[W][0][j + 4] = f2bf(xb0[j]);
            afrag[W][1][j]     = f2bf(xa1[j]);
            afrag[W][1][j + 4] = f2bf(xb1[j]);
        }
    }

    // linear global sources (lane-th 16B chunk of each 1KB row) + swizzled
    // LDS write addresses: physical chunk lane^(r&7) of row r (buf0 base).
    const size_t GS = (size_t)Oq * Nq * Tq;   // g-stride in floats
    const float* wptr[4];
    float* dwp[4];
#pragma unroll
    for (int q = 0; q < 4; ++q) {
        const int r = wv * 4 + q;
        wptr[q] = w + ((size_t)(o0 + r) * Nq + n) * Tq + (lane << 2);
        dwp[q]  = &wbuf[0][r * 256 + ((lane ^ (r & 7)) << 2)];
    }

    // drain all prologue VMEM (x/mask/y) -> in-loop vmcnt counts are exact
    __syncthreads();

    f32x4 regA[4], regB[4];           // regA: even g, regB: odd g (static)
    // A <- g0 ; B <- g1   (sequential pointer: +GS per issue)
#pragma unroll
    for (int q = 0; q < 4; ++q) {
        regA[q] = __builtin_nontemporal_load((const f32x4*)wptr[q]);
        wptr[q] += GS;
    }
#pragma unroll
    for (int q = 0; q < 4; ++q) {
        regB[q] = __builtin_nontemporal_load((const f32x4*)wptr[q]);
        wptr[q] += GS;
    }
    asm volatile("s_waitcnt vmcnt(4)" ::: "memory");   // g0 landed
#pragma unroll
    for (int q = 0; q < 4; ++q) *(f32x4*)dwp[q] = regA[q];   // buf0 <- g0
#pragma unroll
    for (int q = 0; q < 4; ++q) {                            // A <- g2
        regA[q] = __builtin_nontemporal_load((const f32x4*)wptr[q]);
        wptr[q] += GS;
    }
    asm volatile("s_waitcnt lgkmcnt(0)" ::: "memory");
    __builtin_amdgcn_s_barrier();
    __builtin_amdgcn_sched_barrier(0);

    f32x4 facc0 = {0.f, 0.f, 0.f, 0.f};   // b = 0..15 rows (y-weighted)
    f32x4 facc1 = {0.f, 0.f, 0.f, 0.f};   // b = 16..31 rows

    // compute one g from the given LDS buffer row base, accumulate into facc
    auto compute_g = [&](int g, const float* wrow) {
        f32x4 acc0 = {0.f, 0.f, 0.f, 0.f};
        f32x4 acc1 = {0.f, 0.f, 0.f, 0.f};
#pragma unroll
        for (int W = 0; W < 2; ++W) {
            const int c0 = wv * 16 + W * 8 + hi;   // logical 16B-chunk in row
            f32x4 wa4 = *(const f32x4*)(wrow + ((c0 ^ sr) << 2));
            f32x4 wb4 = *(const f32x4*)(wrow + (((c0 + 4) ^ sr) << 2));
            bf16x8 bfr;
#pragma unroll
            for (int j = 0; j < 4; ++j) {
                bfr[j]     = f2bf(wa4[j] * mka[W][j]);
                bfr[j + 4] = f2bf(wb4[j] * mkb[W][j]);
            }
            acc0 = __builtin_amdgcn_mfma_f32_16x16x32_bf16(afrag[W][0], bfr, acc0, 0, 0, 0);
            acc1 = __builtin_amdgcn_mfma_f32_16x16x32_bf16(afrag[W][1], bfr, acc1, 0, 0, 0);
        }
#pragma unroll
        for (int i = 0; i < 4; ++i) {
            facc0[i] += y_lds[(hi * 4 + i) * Gq + g] * acc0[i];
            facc1[i] += y_lds[(16 + hi * 4 + i) * Gq + g] * acc1[i];
        }
    };

    const float* wrow0 = &wbuf[0][lo * 256];
    const float* wrow1 = &wbuf[1][lo * 256];

#pragma unroll 1
    for (int gp = 0; gp < 7; ++gp) {
        // ---- even g = 2gp from buf0
        compute_g(2 * gp, wrow0);
        asm volatile("s_waitcnt vmcnt(4)" ::: "memory");   // regB (2gp+1) landed
#pragma unroll
        for (int q = 0; q < 4; ++q) *(f32x4*)(dwp[q] + 4096) = regB[q];  // buf1
#pragma unroll
        for (int q = 0; q < 4; ++q) {                      // B <- 2gp+3 (<=15)
            regB[q] = __builtin_nontemporal_load((const f32x4*)wptr[q]);
            wptr[q] += GS;
        }
        asm volatile("s_waitcnt lgkmcnt(0)" ::: "memory");
        __builtin_amdgcn_s_barrier();
        __builtin_amdgcn_sched_barrier(0);

        // ---- odd g = 2gp+1 from buf1
        compute_g(2 * gp + 1, wrow1);
        asm volatile("s_waitcnt vmcnt(4)" ::: "memory");   // regA (2gp+2) landed
#pragma unroll
        for (int q = 0; q < 4; ++q) *(f32x4*)dwp[q] = regA[q];           // buf0
        if (gp < 6) {
#pragma unroll
            for (int q = 0; q < 4; ++q) {                  // A <- 2gp+4 (<=14)
                regA[q] = __builtin_nontemporal_load((const f32x4*)wptr[q]);
                wptr[q] += GS;
            }
        }
        asm volatile("s_waitcnt lgkmcnt(0)" ::: "memory");
        __builtin_amdgcn_s_barrier();
        __builtin_amdgcn_sched_barrier(0);
    }

    // ---- tail: g14 from buf0 (written at gp=6 odd half)
    compute_g(14, wrow0);
    asm volatile("s_waitcnt vmcnt(0)" ::: "memory");       // regB (g15): only 4 left
#pragma unroll
    for (int q = 0; q < 4; ++q) *(f32x4*)(dwp[q] + 4096) = regB[q];      // buf1
    asm volatile("s_waitcnt lgkmcnt(0)" ::: "memory");
    __builtin_amdgcn_s_barrier();
    __builtin_amdgcn_sched_barrier(0);
    // ---- g15 from buf1
    compute_g(15, wrow1);

    // cross-wave (t-split) reduction; overlay red[4][32][16] on wbuf[0].
    __syncthreads();
    float (*red)[32][16] = (float (*)[32][16]) & wbuf[0][0];
#pragma unroll
    for (int i = 0; i < 4; ++i) {
        red[wv][hi * 4 + i][lo]      = facc0[i];
        red[wv][16 + hi * 4 + i][lo] = facc1[i];
    }
    __syncthreads();

    // 512 outputs (32 b x 16 o), 256 threads -> 2 each; sum 4 wave-partials
#pragma unroll
    for (int s = 0; s < 2; ++s) {
        const int idx = tid + s * 256;
        const int b  = idx >> 4;
        const int oo = idx & 15;
        const float v = red[0][b][oo] + red[1][b][oo] + red[2][b][oo] + red[3][b][oo]
                      + bias[o0 + oo];
        out[((size_t)b * Nq + n) * Oq + o0 + oo] = v;
    }
}

extern "C" void kernel_launch(void* const* d_in, const int* in_sizes, int n_in,
                              void* d_out, int out_size, void* d_ws, size_t ws_size,
                              hipStream_t stream) {
    const float* x    = (const float*)d_in[0];
    const float* y    = (const float*)d_in[1];
    const float* w    = (const float*)d_in[2];
    const float* mask = (const float*)d_in[3];
    const float* bias = (const float*)d_in[4];
    float* out = (float*)d_out;

    dim3 grid(Nq * (Oq / 16));  // 88 n-slices * 16 o-tiles = 1408 blocks
    dim3 block(256);
    hipLaunchKernelGGL(mlm_mfma10, grid, block, 0, stream, x, y, w, mask, bias, out);
}

// Round 11
// 68.848 us; speedup vs baseline: 1.7301x; 1.7301x over previous
//
#include <hip/hip_runtime.h>

// Sizes (fixed by the reference)
#define Bq 32
#define Gq 16
#define Oq 256
#define Nq 88
#define Tq 256

typedef short bf16x8 __attribute__((ext_vector_type(8)));   // 8 bf16 in 4 VGPRs
typedef float f32x4 __attribute__((ext_vector_type(4)));

static __device__ __forceinline__ short f2bf(float f) {
    return __builtin_bit_cast(short, (__bf16)f);  // RNE convert, bits as short
}

// out[b,n,o] = sum_{g,t} x[b,n,t] * y[b,g] * w[g,o,n,t] * mask[o,t] + bias[o]
//
// R11 = exact revert to R9 (68.7us best). R10's 4-blocks/CU cap spilled
// (VGPR cap 128 < ~150 needed). Little's law says MLP is queue-limited at
// 3 blocks/CU already, so (256,3) is the right operating point.
//  - Weight staging: plain NT global_load_dwordx4 -> VGPR -> ds_write_b128
//    (regA=even g, regB=odd g, static indexing), counted vmcnt(4),
//    raw s_barrier; never drain to 0 until the tail.
//  - XOR swizzle on the ds_write address; reader unchanged (rule 21).
//  - y[b,g] applied per-g to the f32 MFMA partial.
__global__ __launch_bounds__(256, 3)
void mlm_mfma11(const float* __restrict__ x, const float* __restrict__ y,
                const float* __restrict__ w, const float* __restrict__ mask,
                const float* __restrict__ bias, float* __restrict__ out) {
    __shared__ float wbuf[2][4096];   // 2 x 16KB: [16 rows(o)][64 chunks x 4 floats]
    __shared__ float y_lds[512];      // y[b][g] row-major

    const int bid = blockIdx.x;
    const int n  = bid >> 4;          // 0..87
    const int o0 = (bid & 15) << 4;   // o-tile base

    const int tid  = threadIdx.x;
    const int wv   = tid >> 6;        // 0..3 -> t-range [wv*64, wv*64+64)
    const int lane = tid & 63;
    const int lo = lane & 15;         // A row-slot / B col (o) / C col
    const int hi = lane >> 4;         // k-group 0..3
    const int sr = lo & 7;            // read-side swizzle key (o-row = lo)

    y_lds[tid]       = y[tid];
    y_lds[tid + 256] = y[tid + 256];

    // A fragments (x -> bf16) and mask chunks: built once, live for all 16 g.
    // sigma: frag elem (hi,j): j<4 -> t = tA+j ; j>=4 -> t = tA+16+(j-4)
    bf16x8 afrag[2][2];               // [window W][b-half]
    f32x4 mka[2], mkb[2];
    const int tbase = wv * 64;
#pragma unroll
    for (int W = 0; W < 2; ++W) {
        const int ta = tbase + W * 32 + hi * 4;
        const int tb = ta + 16;
        f32x4 xa0 = *(const f32x4*)(x + ((size_t)lo * Nq + n) * Tq + ta);
        f32x4 xb0 = *(const f32x4*)(x + ((size_t)lo * Nq + n) * Tq + tb);
        f32x4 xa1 = *(const f32x4*)(x + ((size_t)(lo + 16) * Nq + n) * Tq + ta);
        f32x4 xb1 = *(const f32x4*)(x + ((size_t)(lo + 16) * Nq + n) * Tq + tb);
        mka[W] = *(const f32x4*)(mask + (size_t)(o0 + lo) * Tq + ta);
        mkb[W] = *(const f32x4*)(mask + (size_t)(o0 + lo) * Tq + tb);
#pragma unroll
        for (int j = 0; j < 4; ++j) {
            afrag[W][0][j]     = f2bf(xa0[j]);
            afrag[W][0][j + 4] = f2bf(xb0[j]);
            afrag[W][1][j]     = f2bf(xa1[j]);
            afrag[W][1][j + 4] = f2bf(xb1[j]);
        }
    }

    // linear global sources (lane-th 16B chunk of each 1KB row) + swizzled
    // LDS write addresses: physical chunk lane^(r&7) of row r (buf0 base).
    const size_t GS = (size_t)Oq * Nq * Tq;   // g-stride in floats
    const float* wptr[4];
    float* dwp[4];
#pragma unroll
    for (int q = 0; q < 4; ++q) {
        const int r = wv * 4 + q;
        wptr[q] = w + ((size_t)(o0 + r) * Nq + n) * Tq + (lane << 2);
        dwp[q]  = &wbuf[0][r * 256 + ((lane ^ (r & 7)) << 2)];
    }

    // drain all prologue VMEM (x/mask/y) -> in-loop vmcnt counts are exact
    __syncthreads();

    f32x4 regA[4], regB[4];           // regA: even g, regB: odd g (static)
    // A <- g0 ; B <- g1   (sequential pointer: +GS per issue)
#pragma unroll
    for (int q = 0; q < 4; ++q) {
        regA[q] = __builtin_nontemporal_load((const f32x4*)wptr[q]);
        wptr[q] += GS;
    }
#pragma unroll
    for (int q = 0; q < 4; ++q) {
        regB[q] = __builtin_nontemporal_load((const f32x4*)wptr[q]);
        wptr[q] += GS;
    }
    asm volatile("s_waitcnt vmcnt(4)" ::: "memory");   // g0 landed
#pragma unroll
    for (int q = 0; q < 4; ++q) *(f32x4*)dwp[q] = regA[q];   // buf0 <- g0
#pragma unroll
    for (int q = 0; q < 4; ++q) {                            // A <- g2
        regA[q] = __builtin_nontemporal_load((const f32x4*)wptr[q]);
        wptr[q] += GS;
    }
    asm volatile("s_waitcnt lgkmcnt(0)" ::: "memory");
    __builtin_amdgcn_s_barrier();
    __builtin_amdgcn_sched_barrier(0);

    f32x4 facc0 = {0.f, 0.f, 0.f, 0.f};   // b = 0..15 rows (y-weighted)
    f32x4 facc1 = {0.f, 0.f, 0.f, 0.f};   // b = 16..31 rows

    // compute one g from the given LDS buffer row base, accumulate into facc
    auto compute_g = [&](int g, const float* wrow) {
        f32x4 acc0 = {0.f, 0.f, 0.f, 0.f};
        f32x4 acc1 = {0.f, 0.f, 0.f, 0.f};
#pragma unroll
        for (int W = 0; W < 2; ++W) {
            const int c0 = wv * 16 + W * 8 + hi;   // logical 16B-chunk in row
            f32x4 wa4 = *(const f32x4*)(wrow + ((c0 ^ sr) << 2));
            f32x4 wb4 = *(const f32x4*)(wrow + (((c0 + 4) ^ sr) << 2));
            bf16x8 bfr;
#pragma unroll
            for (int j = 0; j < 4; ++j) {
                bfr[j]     = f2bf(wa4[j] * mka[W][j]);
                bfr[j + 4] = f2bf(wb4[j] * mkb[W][j]);
            }
            acc0 = __builtin_amdgcn_mfma_f32_16x16x32_bf16(afrag[W][0], bfr, acc0, 0, 0, 0);
            acc1 = __builtin_amdgcn_mfma_f32_16x16x32_bf16(afrag[W][1], bfr, acc1, 0, 0, 0);
        }
#pragma unroll
        for (int i = 0; i < 4; ++i) {
            facc0[i] += y_lds[(hi * 4 + i) * Gq + g] * acc0[i];
            facc1[i] += y_lds[(16 + hi * 4 + i) * Gq + g] * acc1[i];
        }
    };

    const float* wrow0 = &wbuf[0][lo * 256];
    const float* wrow1 = &wbuf[1][lo * 256];

#pragma unroll 1
    for (int gp = 0; gp < 7; ++gp) {
        // ---- even g = 2gp from buf0
        compute_g(2 * gp, wrow0);
        asm volatile("s_waitcnt vmcnt(4)" ::: "memory");   // regB (2gp+1) landed
#pragma unroll
        for (int q = 0; q < 4; ++q) *(f32x4*)(dwp[q] + 4096) = regB[q];  // buf1
#pragma unroll
        for (int q = 0; q < 4; ++q) {                      // B <- 2gp+3 (<=15)
            regB[q] = __builtin_nontemporal_load((const f32x4*)wptr[q]);
            wptr[q] += GS;
        }
        asm volatile("s_waitcnt lgkmcnt(0)" ::: "memory");
        __builtin_amdgcn_s_barrier();
        __builtin_amdgcn_sched_barrier(0);

        // ---- odd g = 2gp+1 from buf1
        compute_g(2 * gp + 1, wrow1);
        asm volatile("s_waitcnt vmcnt(4)" ::: "memory");   // regA (2gp+2) landed
#pragma unroll
        for (int q = 0; q < 4; ++q) *(f32x4*)dwp[q] = regA[q];           // buf0
        if (gp < 6) {
#pragma unroll
            for (int q = 0; q < 4; ++q) {                  // A <- 2gp+4 (<=14)
                regA[q] = __builtin_nontemporal_load((const f32x4*)wptr[q]);
                wptr[q] += GS;
            }
        }
        asm volatile("s_waitcnt lgkmcnt(0)" ::: "memory");
        __builtin_amdgcn_s_barrier();
        __builtin_amdgcn_sched_barrier(0);
    }

    // ---- tail: g14 from buf0 (written at gp=6 odd half)
    compute_g(14, wrow0);
    asm volatile("s_waitcnt vmcnt(0)" ::: "memory");       // regB (g15): only 4 left
#pragma unroll
    for (int q = 0; q < 4; ++q) *(f32x4*)(dwp[q] + 4096) = regB[q];      // buf1
    asm volatile("s_waitcnt lgkmcnt(0)" ::: "memory");
    __builtin_amdgcn_s_barrier();
    __builtin_amdgcn_sched_barrier(0);
    // ---- g15 from buf1
    compute_g(15, wrow1);

    // cross-wave (t-split) reduction; overlay red[4][32][16] on wbuf[0].
    __syncthreads();
    float (*red)[32][16] = (float (*)[32][16]) & wbuf[0][0];
#pragma unroll
    for (int i = 0; i < 4; ++i) {
        red[wv][hi * 4 + i][lo]      = facc0[i];
        red[wv][16 + hi * 4 + i][lo] = facc1[i];
    }
    __syncthreads();

    // 512 outputs (32 b x 16 o), 256 threads -> 2 each; sum 4 wave-partials
#pragma unroll
    for (int s = 0; s < 2; ++s) {
        const int idx = tid + s * 256;
        const int b  = idx >> 4;
        const int oo = idx & 15;
        const float v = red[0][b][oo] + red[1][b][oo] + red[2][b][oo] + red[3][b][oo]
                      + bias[o0 + oo];
        out[((size_t)b * Nq + n) * Oq + o0 + oo] = v;
    }
}

extern "C" void kernel_launch(void* const* d_in, const int* in_sizes, int n_in,
                              void* d_out, int out_size, void* d_ws, size_t ws_size,
                              hipStream_t stream) {
    const float* x    = (const float*)d_in[0];
    const float* y    = (const float*)d_in[1];
    const float* w    = (const float*)d_in[2];
    const float* mask = (const float*)d_in[3];
    const float* bias = (const float*)d_in[4];
    float* out = (float*)d_out;

    dim3 grid(Nq * (Oq / 16));  // 88 n-slices * 16 o-tiles = 1408 blocks
    dim3 block(256);
    hipLaunchKernelGGL(mlm_mfma11, grid, block, 0, stream, x, y, w, mask, bias, out);
}